// Round 1
// baseline (423.735 us; speedup 1.0000x reference)
//
#include <hip/hip_runtime.h>
#include <hip/hip_bf16.h>
#include <stdint.h>

typedef __attribute__((ext_vector_type(4))) float f32x4;
typedef __attribute__((ext_vector_type(8))) short s16x8;

__device__ __forceinline__ ushort f2bf(float f) {
  union { float f; uint32_t u; } v; v.f = f;
  uint32_t r = v.u + 0x7FFFu + ((v.u >> 16) & 1u);
  return (ushort)(r >> 16);
}

__device__ __forceinline__ void gload_lds16(const ushort* g, short* l) {
  __builtin_amdgcn_global_load_lds(
      (const __attribute__((address_space(1))) uint32_t*)g,
      (__attribute__((address_space(3))) uint32_t*)l, 16, 0, 0);
}

// C[128,128] tile of A[M,K] * Bt[N,K]^T, bf16 in, fp32 acc.
// 256 threads = 4 waves (2x2), each wave 64x64 = 4x4 frags of 16x16x32 MFMA.
__device__ __forceinline__ void gemm_tile(
    const ushort* A, int lda, const ushort* Bt, int ldb,
    int m0, int n0, int ksteps, short* As, short* Bs, f32x4 acc[4][4])
{
  const int tid  = threadIdx.x;
  const int lane = tid & 63;
  const int wr   = (tid >> 7) & 1;
  const int wc   = (tid >> 6) & 1;

#pragma unroll
  for (int i = 0; i < 4; ++i)
#pragma unroll
    for (int j = 0; j < 4; ++j)
      acc[i][j] = (f32x4){0.f, 0.f, 0.f, 0.f};

  const int fr = lane & 15;
  const int kg = (lane >> 4) << 3;
  const short* Ab = As + (wr * 64 + fr) * 64 + kg;
  const short* Bb = Bs + (wc * 64 + fr) * 64 + kg;

  const int srow = tid >> 3;          // staging row within 32-row chunk
  const int scol = (tid & 7) << 3;    // staging col (elements)

  for (int kk = 0; kk < ksteps; ++kk) {
    const size_t k0 = (size_t)kk << 6;
    __syncthreads();
#pragma unroll
    for (int it = 0; it < 4; ++it) {
      const int r = it * 32 + srow;
      gload_lds16(A  + (size_t)(m0 + r) * lda + k0 + scol, As + (size_t)(it * 256 + tid) * 8);
      gload_lds16(Bt + (size_t)(n0 + r) * ldb + k0 + scol, Bs + (size_t)(it * 256 + tid) * 8);
    }
    __syncthreads();  // compiler drains vmcnt before s_barrier

    s16x8 af[2][4], bf[2][4];
#pragma unroll
    for (int h = 0; h < 2; ++h)
#pragma unroll
      for (int i = 0; i < 4; ++i) {
        af[h][i] = *(const s16x8*)(Ab + i * 1024 + h * 32);
        bf[h][i] = *(const s16x8*)(Bb + i * 1024 + h * 32);
      }
#pragma unroll
    for (int h = 0; h < 2; ++h)
#pragma unroll
      for (int mi = 0; mi < 4; ++mi)
#pragma unroll
        for (int ni = 0; ni < 4; ++ni)
          acc[mi][ni] = __builtin_amdgcn_mfma_f32_16x16x32_bf16(
              af[h][mi], bf[h][ni], acc[mi][ni], 0, 0, 0);
  }
}

__global__ void cvt_x(const float* __restrict__ x, ushort* __restrict__ xb)
{
  const size_t i = (size_t)(blockIdx.x * 256 + threadIdx.x) * 4;
  const f32x4 t = *(const f32x4*)(x + i);
  uint2 pk;
  pk.x = (uint32_t)f2bf(t[0]) | ((uint32_t)f2bf(t[1]) << 16);
  pk.y = (uint32_t)f2bf(t[2]) | ((uint32_t)f2bf(t[3]) << 16);
  *(uint2*)(xb + i) = pk;
}

// wt[z][n][k] = bf16(w_z[k][n]);  z: 0=q_wei, 1=k_wei, 2=v_wei
__global__ void cvt_w(const float* __restrict__ kw, const float* __restrict__ qw,
                      const float* __restrict__ vw, ushort* __restrict__ wt)
{
  __shared__ float t[32][33];
  const float* w = (blockIdx.z == 0) ? qw : (blockIdx.z == 1) ? kw : vw;
  const int n0 = blockIdx.x * 32, k0 = blockIdx.y * 32;
  t[threadIdx.y][threadIdx.x] = w[(size_t)(k0 + threadIdx.y) * 1024 + n0 + threadIdx.x];
  __syncthreads();
  wt[(size_t)blockIdx.z * 1048576 + (size_t)(n0 + threadIdx.y) * 1024 + k0 + threadIdx.x] =
      f2bf(t[threadIdx.x][threadIdx.y]);
}

__global__ __launch_bounds__(256) void gemm_qkv(
    const ushort* __restrict__ xb, const ushort* __restrict__ wt,
    ushort* __restrict__ q, ushort* __restrict__ k, ushort* __restrict__ vT)
{
  __attribute__((aligned(16))) __shared__ short As[8192], Bs[8192];
  const int n0 = blockIdx.x * 128;
  const int m0 = blockIdx.y * 128;
  const int z  = blockIdx.z;
  f32x4 acc[4][4];
  gemm_tile(xb, 1024, wt + (size_t)z * 1048576, 1024, m0, n0, 16, As, Bs, acc);

  const int lane = threadIdx.x & 63;
  const int wr = (threadIdx.x >> 7) & 1, wc = (threadIdx.x >> 6) & 1;
  const int r0 = m0 + wr * 64 + ((lane >> 4) << 2);
  const int c0 = n0 + wc * 64 + (lane & 15);
  ushort* o = (z == 0) ? q : k;
#pragma unroll
  for (int mi = 0; mi < 4; ++mi)
#pragma unroll
    for (int ni = 0; ni < 4; ++ni)
#pragma unroll
      for (int j = 0; j < 4; ++j) {
        const int r = r0 + mi * 16 + j;
        const int c = c0 + ni * 16;
        const ushort hv = f2bf(acc[mi][ni][j]);
        if (z < 2) o[(size_t)r * 1024 + c] = hv;
        else       vT[((size_t)(r >> 11) * 1024 + c) * 2048 + (r & 2047)] = hv;
      }
}

__global__ __launch_bounds__(256) void gemm_s(
    const ushort* __restrict__ q, const ushort* __restrict__ k, float* __restrict__ S)
{
  const int kt = blockIdx.x, qt = blockIdx.y, b = blockIdx.z;
  if (kt > qt) return;  // causal: whole tile masked
  __attribute__((aligned(16))) __shared__ short As[8192], Bs[8192];
  f32x4 acc[4][4];
  const ushort* qb = q + (size_t)b * (2048 * 1024);
  const ushort* kb = k + (size_t)b * (2048 * 1024);
  gemm_tile(qb, 1024, kb, 1024, qt * 128, kt * 128, 16, As, Bs, acc);

  float* Sb = S + (size_t)b * 4194304;
  const int lane = threadIdx.x & 63;
  const int wr = (threadIdx.x >> 7) & 1, wc = (threadIdx.x >> 6) & 1;
  const int r0 = qt * 128 + wr * 64 + ((lane >> 4) << 2);
  const int c0 = kt * 128 + wc * 64 + (lane & 15);
#pragma unroll
  for (int mi = 0; mi < 4; ++mi)
#pragma unroll
    for (int ni = 0; ni < 4; ++ni)
#pragma unroll
      for (int j = 0; j < 4; ++j)
        Sb[(size_t)(r0 + mi * 16 + j) * 2048 + (c0 + ni * 16)] = acc[mi][ni][j];
}

// one wave per row; reads S fp32, writes P bf16 in place (same row base).
__global__ __launch_bounds__(256) void softmax_k(float* __restrict__ S)
{
  const int row  = blockIdx.x * 4 + (threadIdx.x >> 6);
  const int lane = threadIdx.x & 63;
  const int L = (row & 2047) + 1;  // valid keys = query_index + 1
  float* srow = S + (size_t)row * 2048;
  float v[32];
#pragma unroll
  for (int it = 0; it < 8; ++it) {
    const int j0 = (it * 64 + lane) * 4;
    const f32x4 t = *(const f32x4*)(srow + j0);
#pragma unroll
    for (int u = 0; u < 4; ++u) v[it * 4 + u] = (j0 + u < L) ? t[u] : -1e30f;
  }
  float m = v[0];
#pragma unroll
  for (int i = 1; i < 32; ++i) m = fmaxf(m, v[i]);
#pragma unroll
  for (int off = 32; off > 0; off >>= 1) m = fmaxf(m, __shfl_xor(m, off));
  float sum = 0.f;
#pragma unroll
  for (int i = 0; i < 32; ++i) {
    const float e = (v[i] > -1e29f) ? __expf((v[i] - m) * 0.03125f) : 0.f;
    v[i] = e; sum += e;
  }
#pragma unroll
  for (int off = 32; off > 0; off >>= 1) sum += __shfl_xor(sum, off);
  const float rs = 1.f / sum;
  ushort* prow = (ushort*)srow;
#pragma unroll
  for (int it = 0; it < 8; ++it) {
    const int j0 = (it * 64 + lane) * 4;
    uint2 pk;
    pk.x = (uint32_t)f2bf(v[it*4+0] * rs) | ((uint32_t)f2bf(v[it*4+1] * rs) << 16);
    pk.y = (uint32_t)f2bf(v[it*4+2] * rs) | ((uint32_t)f2bf(v[it*4+3] * rs) << 16);
    *(uint2*)(prow + j0) = pk;
  }
}

__global__ __launch_bounds__(256) void gemm_pv(
    const ushort* __restrict__ P, const ushort* __restrict__ vT, float* __restrict__ out)
{
  const int ht = blockIdx.x, qt = blockIdx.y, b = blockIdx.z;
  __attribute__((aligned(16))) __shared__ short As[8192], Bs[8192];
  f32x4 acc[4][4];
  const ushort* Pb = P  + (size_t)b * (2048 * 4096);  // P rows stride 4096 elems (in S buffer)
  const ushort* Vb = vT + (size_t)b * (1024 * 2048);
  gemm_tile(Pb, 4096, Vb, 2048, qt * 128, ht * 128, (qt + 1) * 2, As, Bs, acc);

  float* ob = out + (size_t)b * 2097152;
  const int lane = threadIdx.x & 63;
  const int wr = (threadIdx.x >> 7) & 1, wc = (threadIdx.x >> 6) & 1;
  const int r0 = qt * 128 + wr * 64 + ((lane >> 4) << 2);
  const int c0 = ht * 128 + wc * 64 + (lane & 15);
#pragma unroll
  for (int mi = 0; mi < 4; ++mi)
#pragma unroll
    for (int ni = 0; ni < 4; ++ni)
#pragma unroll
      for (int j = 0; j < 4; ++j)
        ob[(size_t)(r0 + mi * 16 + j) * 1024 + (c0 + ni * 16)] = acc[mi][ni][j];
}

extern "C" void kernel_launch(void* const* d_in, const int* in_sizes, int n_in,
                              void* d_out, int out_size, void* d_ws, size_t ws_size,
                              hipStream_t stream)
{
  const float* x  = (const float*)d_in[0];
  const float* kw = (const float*)d_in[1];
  const float* qw = (const float*)d_in[2];
  const float* vw = (const float*)d_in[3];
  float* out = (float*)d_out;
  char* ws = (char*)d_ws;

  ushort* xb = (ushort*)ws;                    // 32MB, aliases S (consumed before S written)
  float*  S  = (float*)ws;                     // 128MB fp32 scores; P bf16 written in place
  ushort* wt = (ushort*)(ws + 134217728);      // 6MB  transposed bf16 weights
  ushort* q  = (ushort*)(ws + 140509184);      // 32MB
  ushort* k  = (ushort*)(ws + 174063616);      // 32MB
  ushort* vT = (ushort*)(ws + 207618048);      // 32MB [B][HS][T]

  cvt_x<<<16384, 256, 0, stream>>>(x, xb);
  cvt_w<<<dim3(32, 32, 3), dim3(32, 32), 0, stream>>>(kw, qw, vw, wt);
  gemm_qkv<<<dim3(8, 128, 3), 256, 0, stream>>>(xb, wt, q, k, vT);
  gemm_s<<<dim3(16, 16, 8), 256, 0, stream>>>(q, k, S);
  softmax_k<<<4096, 256, 0, stream>>>(S);
  gemm_pv<<<dim3(8, 16, 8), 256, 0, stream>>>((const ushort*)ws, vT, out);
}